// Round 7
// baseline (359.526 us; speedup 1.0000x reference)
//
#include <hip/hip_runtime.h>

typedef unsigned short u16;
typedef unsigned int   u32;
typedef __bf16 v8bf __attribute__((ext_vector_type(8)));
typedef float  v4f  __attribute__((ext_vector_type(4)));

#define INV_SQRT_W   0.044194173824159216f   // 1/sqrt(512)
#define INV_SQRT_KKC 0.029462782549439483f   // 1/sqrt(3*3*128)
#define LRELU_GAIN   1.4142135623730951f

__device__ __forceinline__ u16 f2bf(float f) {
    u32 u = __float_as_uint(f);
    u = (u + 0x7fffu + ((u >> 16) & 1u)) >> 16;   // RNE
    return (u16)u;
}

// ---------------- kernel S: s[n,i] = z @ (aw/sqrt(512)) + ab ----------------
__global__ void k_s(const float* __restrict__ dlat,
                    const float* __restrict__ aw,
                    const float* __restrict__ ab,
                    const int*   __restrict__ lidx,
                    float* __restrict__ s_out)
{
    const int n   = blockIdx.x;      // 8
    const int tid = threadIdx.x;     // 256
    const int i   = tid & 127, kh = tid >> 7;
    const int li  = lidx[0];
    const float* z = dlat + (n * 16 + li) * 512 + kh * 256;
    const float* a = aw + kh * 256 * 128 + i;
    float a0 = 0.f, a1 = 0.f, a2 = 0.f, a3 = 0.f;
    for (int k = 0; k < 256; k += 4) {
        a0 += z[k + 0] * a[(k + 0) * 128];
        a1 += z[k + 1] * a[(k + 1) * 128];
        a2 += z[k + 2] * a[(k + 2) * 128];
        a3 += z[k + 3] * a[(k + 3) * 128];
    }
    __shared__ float part[256];
    part[tid] = a0 + a1 + a2 + a3;
    __syncthreads();
    if (tid < 128)
        s_out[n * 128 + i] = (part[i] + part[i + 128]) * INV_SQRT_W + ab[i];
}

// ---------------- kernel W2: W2[i,o] = sum_t (cw[t,i,o]*inv)^2 ----------------
__global__ void k_w2(const float* __restrict__ cw, float* __restrict__ W2)
{
    const int idx = blockIdx.x * 256 + threadIdx.x;   // 16384 = i*128+o
    float acc = 0.f;
    #pragma unroll
    for (int t = 0; t < 9; ++t) {
        float w = cw[t * 16384 + idx];
        acc += w * w;
    }
    W2[idx] = acc * (INV_SQRT_KKC * INV_SQRT_KKC);
}

// ---------------- kernel D: d[n,o] = rsqrt(sum_i W2[i,o]*s2[n,i] + 1e-8) ----------------
__global__ void k_d(const float* __restrict__ W2,
                    const float* __restrict__ s_buf,
                    float* __restrict__ d_out)
{
    const int n = blockIdx.x;   // 8
    const int o = threadIdx.x;  // 128
    __shared__ float s2[128];
    float sv = s_buf[n * 128 + o];
    s2[o] = sv * sv;
    __syncthreads();
    float acc = 1e-8f;
    #pragma unroll 4
    for (int i = 0; i < 128; ++i)
        acc += W2[i * 128 + o] * s2[i];
    d_out[n * 128 + o] = 1.0f / sqrtf(acc);
}

// -------- kernel WMOD: 8KB weight stages, layout [g:4][cout:128][8ci] bf16 --------
// stage s (0..35): ph=s/18, r=s%18, q2=r/9, rr=r%9, tw=rr/3, th=rr%3,
// tap = th*3+tw, cibase = ph*64 + q2*32.
__global__ void k_wmod(const float* __restrict__ cw,
                       const float* __restrict__ s_buf,
                       const float* __restrict__ d_buf,
                       u16* __restrict__ wmod)
{
    const int b   = blockIdx.x;          // 288 = n*36 + s
    const int n   = b / 36;
    const int s   = b - n * 36;
    const int ph  = s / 18;
    const int r   = s - ph * 18;
    const int q2  = r / 9;
    const int rr  = r - q2 * 9;
    const int tw  = rr / 3, th = rr - tw * 3;
    const int tap = th * 3 + tw;
    const int cibase = ph * 64 + q2 * 32;
    const int tid = threadIdx.x;         // 256
    __shared__ float ssh[32], dsh[128];
    if (tid < 32)  ssh[tid] = s_buf[n * 128 + cibase + tid] * INV_SQRT_KKC;
    if (tid < 128) dsh[tid] = d_buf[n * 128 + tid];
    __syncthreads();
    u16* wt = wmod + ((size_t)b << 12);   // 4096 u16 per stage
    #pragma unroll
    for (int rep = 0; rep < 2; ++rep) {
        int t2   = rep * 256 + tid;       // 512 (g,cout) pairs
        int g    = t2 >> 7;
        int cout = t2 & 127;
        float dv = dsh[cout];
        u32 pk[4];
        #pragma unroll
        for (int jj = 0; jj < 4; ++jj) {
            int cl = g * 8 + jj * 2;
            float v0 = cw[((tap * 128 + cibase + cl) << 7) + cout]     * ssh[cl]     * dv;
            float v1 = cw[((tap * 128 + cibase + cl + 1) << 7) + cout] * ssh[cl + 1] * dv;
            pk[jj] = (u32)f2bf(v0) | ((u32)f2bf(v1) << 16);
        }
        *(uint4*)&wt[(g << 10) + (cout << 3)] = *(uint4*)pk;
    }
}

// ---------------- kernel CONV (template ablation: DO_STAGE) ----------------
// Identical to round-6 structure. DO_STAGE=0 compiles out the x staging
// (xs read uninitialized; ds_reads, B-loads, MFMAs, epilogue all kept) —
// launched FIRST, fully overwritten by the DO_STAGE=1 launch.
template<int T>
__device__ __forceinline__ void conv_step(const u16* __restrict__ bp,
                                          const u16* a_base,
                                          v8bf af[10], v8bf bfP[3][4],
                                          v4f acc[8][4])
{
    constexpr int q2 = T / 9, rr = T % 9, tw = rr / 3, th = rr % 3;
    constexpr int slot = T % 3;
    if constexpr (th == 0) {
        #pragma unroll
        for (int r = 0; r < 10; ++r)
            af[r] = *(const v8bf*)(a_base + q2 * 10400 + r * 144 + tw * 8);
    }
    #pragma unroll
    for (int mi = 0; mi < 8; ++mi)
        #pragma unroll
        for (int ni = 0; ni < 4; ++ni)
            acc[mi][ni] = __builtin_amdgcn_mfma_f32_16x16x32_bf16(
                af[mi + th], bfP[slot][ni], acc[mi][ni], 0, 0, 0);
    if constexpr (T + 3 < 18) {
        #pragma unroll
        for (int ni = 0; ni < 4; ++ni)
            bfP[slot][ni] = *(const v8bf*)(bp + (T + 3) * 4096 + ni * 128);
    }
}

template<int DO_STAGE>
__global__ __launch_bounds__(256, 2) void k_conv(
    const float* __restrict__ x,
    const float* __restrict__ noise,
    const float* __restrict__ conv_b,
    const float* __restrict__ nstr,
    const u16*   __restrict__ wmod,
    float* __restrict__ out)
{
    __shared__ __align__(16) u16 xs[20800];   // 8 slabs x 2600 u16

    const int bid0 = blockIdx.x;
    const int bid  = ((bid0 & 7) << 8) + (bid0 >> 3);   // XCD swizzle (2048%8==0)
    const int n  = bid >> 8;
    const int hb = (bid >> 4) & 15;
    const int wb = bid & 15;
    const int h0 = hb << 4, w0 = wb << 4;

    const int tid  = threadIdx.x;
    const int lane = tid & 63;
    const int wid  = tid >> 6;
    const int wm   = wid >> 1;         // M half (rows wm*8..wm*8+7)
    const int wq   = wid & 1;          // N half (couts wq*64..)
    const int lr   = lane & 15;
    const int kg   = lane >> 4;

    const float* xbase = x + ((size_t)n << 16) * 128;

    #define STAGE_X(ph)                                                              \
    if constexpr (DO_STAGE) {                                                        \
    for (int t = tid; t < 2592; t += 256) {                                          \
        int q = t >> 3, g = t & 7;                                                   \
        int rr_ = q / 18, cc = q - rr_ * 18;                                         \
        int gh = h0 + rr_ - 1, gw = w0 + cc - 1;                                     \
        float v0=0.f,v1=0.f,v2=0.f,v3=0.f,v4=0.f,v5=0.f,v6=0.f,v7=0.f;               \
        if ((unsigned)gh < 256u && (unsigned)gw < 256u) {                            \
            const float* src = xbase + (size_t)((gh << 8) + gw) * 128                \
                               + (ph) * 64 + (g << 3);                               \
            float4 fa = *(const float4*)(src);                                       \
            float4 fb = *(const float4*)(src + 4);                                   \
            v0=fa.x; v1=fa.y; v2=fa.z; v3=fa.w; v4=fb.x; v5=fb.y; v6=fb.z; v7=fb.w;  \
        }                                                                            \
        v8bf pk;                                                                     \
        pk[0]=(__bf16)v0; pk[1]=(__bf16)v1; pk[2]=(__bf16)v2; pk[3]=(__bf16)v3;      \
        pk[4]=(__bf16)v4; pk[5]=(__bf16)v5; pk[6]=(__bf16)v6; pk[7]=(__bf16)v7;      \
        *(v8bf*)&xs[g * 2600 + q * 8] = pk;                                          \
    } }

    u16* const a_base = &xs[kg * 2600 + (wm * 144 + lr) * 8];
    const u16* const b_base = wmod + (size_t)n * 147456 + kg * 1024 + (wq * 64 + lr) * 8;

    v4f acc[8][4];
    #pragma unroll
    for (int a = 0; a < 8; ++a)
        #pragma unroll
        for (int b2 = 0; b2 < 4; ++b2) {
            v4f zz = {0.f, 0.f, 0.f, 0.f};
            acc[a][b2] = zz;
        }
    v8bf af[10];
    v8bf bfP[3][4];

    #pragma unroll 1
    for (int ph = 0; ph < 2; ++ph) {
        if (ph) __syncthreads();          // all waves done reading xs phase 0
        STAGE_X(ph)
        const u16* bp = b_base + ph * 73728;   // 18 stages * 4096 u16
        #pragma unroll
        for (int t3 = 0; t3 < 3; ++t3)         // prefetch steps 0..2
            #pragma unroll
            for (int ni = 0; ni < 4; ++ni)
                bfP[t3][ni] = *(const v8bf*)(bp + t3 * 4096 + ni * 128);
        __syncthreads();                  // xs phase ready

        conv_step< 0>(bp, a_base, af, bfP, acc);
        conv_step< 1>(bp, a_base, af, bfP, acc);
        conv_step< 2>(bp, a_base, af, bfP, acc);
        conv_step< 3>(bp, a_base, af, bfP, acc);
        conv_step< 4>(bp, a_base, af, bfP, acc);
        conv_step< 5>(bp, a_base, af, bfP, acc);
        conv_step< 6>(bp, a_base, af, bfP, acc);
        conv_step< 7>(bp, a_base, af, bfP, acc);
        conv_step< 8>(bp, a_base, af, bfP, acc);
        conv_step< 9>(bp, a_base, af, bfP, acc);
        conv_step<10>(bp, a_base, af, bfP, acc);
        conv_step<11>(bp, a_base, af, bfP, acc);
        conv_step<12>(bp, a_base, af, bfP, acc);
        conv_step<13>(bp, a_base, af, bfP, acc);
        conv_step<14>(bp, a_base, af, bfP, acc);
        conv_step<15>(bp, a_base, af, bfP, acc);
        conv_step<16>(bp, a_base, af, bfP, acc);
        conv_step<17>(bp, a_base, af, bfP, acc);
    }

    // ---- epilogue: + noise*strength + bias, lrelu * sqrt(2) ----
    const float ns = nstr[0];
    float cb4[4];
    #pragma unroll
    for (int ni = 0; ni < 4; ++ni)
        cb4[ni] = conv_b[wq * 64 + ni * 16 + lr];
    #pragma unroll
    for (int mi = 0; mi < 8; ++mi) {
        const int h = h0 + wm * 8 + mi;
        #pragma unroll
        for (int j = 0; j < 4; ++j) {
            const int w  = w0 + kg * 4 + j;
            const float nz = noise[((n << 8) + h) * 256 + w] * ns;
            float* orow = out + (size_t)((((n << 8) + h) << 8) + w) * 128;
            #pragma unroll
            for (int ni = 0; ni < 4; ++ni) {
                const int cout = wq * 64 + ni * 16 + lr;
                float v = acc[mi][ni][j] + nz + cb4[ni];
                v = (v < 0.f ? 0.2f * v : v) * LRELU_GAIN;
                orow[cout] = v;
            }
        }
    }
}

extern "C" void kernel_launch(void* const* d_in, const int* in_sizes, int n_in,
                              void* d_out, int out_size, void* d_ws, size_t ws_size,
                              hipStream_t stream) {
    const float* x     = (const float*)d_in[0];
    const float* dlat  = (const float*)d_in[1];
    const float* noise = (const float*)d_in[2];
    const float* aw    = (const float*)d_in[3];
    const float* ab    = (const float*)d_in[4];
    const float* cw    = (const float*)d_in[5];
    const float* cb    = (const float*)d_in[6];
    const float* nstr  = (const float*)d_in[7];
    const int*   lidx  = (const int*)d_in[8];
    float* out = (float*)d_out;

    float* s_buf = (float*)d_ws;                               // 4KB
    float* d_buf = (float*)((char*)d_ws + 4096);               // 4KB
    float* W2    = (float*)((char*)d_ws + 8192);
    u16*   wmod  = (u16*)((char*)d_ws + 8192);                 // 2.25MB

    k_w2  <<<64,  256, 0, stream>>>(cw, W2);
    k_s   <<<8,   256, 0, stream>>>(dlat, aw, ab, lidx, s_buf);
    k_d   <<<8,   128, 0, stream>>>(W2, s_buf, d_buf);
    k_wmod<<<288, 256, 0, stream>>>(cw, s_buf, d_buf, wmod);
    // ABLATION: NOSTAGE variant first (garbage output, fully overwritten below).
    // Its dur = total - (table k_conv<1> dur) - ~8us pre-kernels.
    k_conv<0><<<2048,256, 0, stream>>>(x, noise, cb, nstr, wmod, out);
    // Real kernel last: writes every output element -> validation sees only this.
    k_conv<1><<<2048,256, 0, stream>>>(x, noise, cb, nstr, wmod, out);
}

// Round 8
// 225.531 us; speedup vs baseline: 1.5941x; 1.5941x over previous
//
#include <hip/hip_runtime.h>

typedef unsigned short u16;
typedef unsigned int   u32;
typedef __bf16 v8bf __attribute__((ext_vector_type(8)));
typedef float  v4f  __attribute__((ext_vector_type(4)));

#define INV_SQRT_W   0.044194173824159216f   // 1/sqrt(512)
#define INV_SQRT_KKC 0.029462782549439483f   // 1/sqrt(3*3*128)
#define LRELU_GAIN   1.4142135623730951f

__device__ __forceinline__ u16 f2bf(float f) {
    u32 u = __float_as_uint(f);
    u = (u + 0x7fffu + ((u >> 16) & 1u)) >> 16;   // RNE
    return (u16)u;
}

// ---------------- kernel S: s[n,i] = z @ (aw/sqrt(512)) + ab ----------------
__global__ void k_s(const float* __restrict__ dlat,
                    const float* __restrict__ aw,
                    const float* __restrict__ ab,
                    const int*   __restrict__ lidx,
                    float* __restrict__ s_out)
{
    const int n   = blockIdx.x;      // 8
    const int tid = threadIdx.x;     // 256
    const int i   = tid & 127, kh = tid >> 7;
    const int li  = lidx[0];
    const float* z = dlat + (n * 16 + li) * 512 + kh * 256;
    const float* a = aw + kh * 256 * 128 + i;
    float a0 = 0.f, a1 = 0.f, a2 = 0.f, a3 = 0.f;
    for (int k = 0; k < 256; k += 4) {
        a0 += z[k + 0] * a[(k + 0) * 128];
        a1 += z[k + 1] * a[(k + 1) * 128];
        a2 += z[k + 2] * a[(k + 2) * 128];
        a3 += z[k + 3] * a[(k + 3) * 128];
    }
    __shared__ float part[256];
    part[tid] = a0 + a1 + a2 + a3;
    __syncthreads();
    if (tid < 128)
        s_out[n * 128 + i] = (part[i] + part[i + 128]) * INV_SQRT_W + ab[i];
}

// ---------------- kernel W2: W2[i,o] = sum_t (cw[t,i,o]*inv)^2 ----------------
__global__ void k_w2(const float* __restrict__ cw, float* __restrict__ W2)
{
    const int idx = blockIdx.x * 256 + threadIdx.x;   // 16384 = i*128+o
    float acc = 0.f;
    #pragma unroll
    for (int t = 0; t < 9; ++t) {
        float w = cw[t * 16384 + idx];
        acc += w * w;
    }
    W2[idx] = acc * (INV_SQRT_KKC * INV_SQRT_KKC);
}

// ---------------- kernel D: d[n,o] = rsqrt(sum_i W2[i,o]*s2[n,i] + 1e-8) ----------------
__global__ void k_d(const float* __restrict__ W2,
                    const float* __restrict__ s_buf,
                    float* __restrict__ d_out)
{
    const int n = blockIdx.x;   // 8
    const int o = threadIdx.x;  // 128
    __shared__ float s2[128];
    float sv = s_buf[n * 128 + o];
    s2[o] = sv * sv;
    __syncthreads();
    float acc = 1e-8f;
    #pragma unroll 4
    for (int i = 0; i < 128; ++i)
        acc += W2[i * 128 + o] * s2[i];
    d_out[n * 128 + o] = 1.0f / sqrtf(acc);
}

// -------- kernel WMOD: 36 stages of 8KB, layout [g:4][cout:128][8ci] bf16 --------
// stage s = q4*9 + tw*3 + th  (q4: 32-ci block, tap = th*3+tw).
// elem(g, cout, j) = cw[tap][q4*32+g*8+j][cout] * inv * s[ci] * d[cout]
__global__ void k_wmod(const float* __restrict__ cw,
                       const float* __restrict__ s_buf,
                       const float* __restrict__ d_buf,
                       u16* __restrict__ wmod)
{
    const int b   = blockIdx.x;          // 288 = n*36 + s
    const int n   = b / 36;
    const int s   = b - n * 36;
    const int q4  = s / 9;
    const int r   = s - q4 * 9;
    const int tw  = r / 3, th = r - tw * 3;
    const int tap = th * 3 + tw;
    const int cibase = q4 * 32;
    const int tid = threadIdx.x;         // 256
    __shared__ float ssh[32], dsh[128];
    if (tid < 32)  ssh[tid] = s_buf[n * 128 + cibase + tid] * INV_SQRT_KKC;
    if (tid < 128) dsh[tid] = d_buf[n * 128 + tid];
    __syncthreads();
    u16* wt = wmod + ((size_t)b << 12);   // 4096 u16 per stage
    #pragma unroll
    for (int rep = 0; rep < 2; ++rep) {
        int t2   = rep * 256 + tid;       // 512 (g,cout) pairs
        int g    = t2 >> 7;
        int cout = t2 & 127;
        float dv = dsh[cout];
        u32 pk[4];
        #pragma unroll
        for (int jj = 0; jj < 4; ++jj) {
            int cl = g * 8 + jj * 2;
            float v0 = cw[((tap * 128 + cibase + cl) << 7) + cout]     * ssh[cl]     * dv;
            float v1 = cw[((tap * 128 + cibase + cl + 1) << 7) + cout] * ssh[cl + 1] * dv;
            pk[jj] = (u32)f2bf(v0) | ((u32)f2bf(v1) << 16);
        }
        *(uint4*)&wt[(g << 10) + (cout << 3)] = *(uint4*)pk;
    }
}

// ---------------- kernel CONV: one-barrier, full-ci halo, B from global ----------------
// 256 thr = 4 waves (2M x 2N); block tile 128 px (8h x 16w) x 128 cout; grid 4096.
// Wave: 64 px x 64 cout, acc[4][4] = 64 AGPR. A via LDS halo 10x18x128ci (45.5KB,
// slab = [q4*4+kg][180 q][8ci], stride 1456 u16) staged ONCE -> 3 blocks/CU.
// th-reuse: 6 ds_reads per 48 MFMA (128 B/MFMA). B: global->reg 2-deep prefetch.
// Exactly ONE __syncthreads in the kernel.
template<int T>
__device__ __forceinline__ void conv_step(const u16* __restrict__ bp,
                                          const u16* a_base,
                                          v8bf af[6], v8bf bfP[2][4],
                                          v4f acc[4][4])
{
    constexpr int q4 = T / 9, rr = T % 9, tw = rr / 3, th = rr % 3;
    constexpr int slot = T & 1;
    if constexpr (th == 0) {
        #pragma unroll
        for (int r = 0; r < 6; ++r)
            af[r] = *(const v8bf*)(a_base + q4 * 5824 + (r * 18 + tw) * 8);
    }
    #pragma unroll
    for (int mi = 0; mi < 4; ++mi)
        #pragma unroll
        for (int ni = 0; ni < 4; ++ni)
            acc[mi][ni] = __builtin_amdgcn_mfma_f32_16x16x32_bf16(
                af[mi + th], bfP[slot][ni], acc[mi][ni], 0, 0, 0);
    if constexpr (T + 2 < 36) {
        #pragma unroll
        for (int ni = 0; ni < 4; ++ni)
            bfP[slot][ni] = *(const v8bf*)(bp + (T + 2) * 4096 + ni * 128);
    }
}

__global__ __launch_bounds__(256, 3) void k_conv(
    const float* __restrict__ x,
    const float* __restrict__ noise,
    const float* __restrict__ conv_b,
    const float* __restrict__ nstr,
    const u16*   __restrict__ wmod,
    float* __restrict__ out)
{
    __shared__ __align__(16) u16 xs[23296];   // 16 slabs x 1456 u16 (180 q x 8ci + pad)

    const int bid0 = blockIdx.x;
    const int bid  = ((bid0 & 7) << 9) + (bid0 >> 3);   // XCD swizzle (4096%8==0, bijective)
    const int n  = bid >> 9;
    const int hb = (bid >> 4) & 31;
    const int wb = bid & 15;
    const int h0 = hb << 3, w0 = wb << 4;

    const int tid  = threadIdx.x;
    const int lane = tid & 63;
    const int wid  = tid >> 6;
    const int wm   = wid >> 1;         // M half (output rows wm*4..wm*4+3)
    const int wq   = wid & 1;          // N half (couts wq*64..)
    const int lr   = lane & 15;
    const int kg   = lane >> 4;

    const float* xbase = x + ((size_t)n << 16) * 128;
    const u16* const b_base = wmod + (size_t)n * 147456 + kg * 1024 + (wq * 64 + lr) * 8;

    // ---- B prologue: prefetch stages 0,1 into regs (independent of LDS) ----
    v8bf bfP[2][4];
    #pragma unroll
    for (int t2 = 0; t2 < 2; ++t2)
        #pragma unroll
        for (int ni = 0; ni < 4; ++ni)
            bfP[t2][ni] = *(const v8bf*)(b_base + t2 * 4096 + ni * 128);

    // ---- stage X halo (10 x 18 x 128ci) fp32 -> bf16, granule slabs ----
    // t = q*16 + g: 16 lanes (g) read 512B contiguous per pixel q.
    for (int t = tid; t < 2880; t += 256) {
        int g = t & 15, q = t >> 4;
        int rr_ = q / 18, cc = q - rr_ * 18;
        int gh = h0 + rr_ - 1, gw = w0 + cc - 1;
        float v0=0.f,v1=0.f,v2=0.f,v3=0.f,v4=0.f,v5=0.f,v6=0.f,v7=0.f;
        if ((unsigned)gh < 256u && (unsigned)gw < 256u) {
            const float* src = xbase + (size_t)((gh << 8) + gw) * 128 + (g << 3);
            float4 fa = *(const float4*)(src);
            float4 fb = *(const float4*)(src + 4);
            v0=fa.x; v1=fa.y; v2=fa.z; v3=fa.w; v4=fb.x; v5=fb.y; v6=fb.z; v7=fb.w;
        }
        v8bf pk;
        pk[0]=(__bf16)v0; pk[1]=(__bf16)v1; pk[2]=(__bf16)v2; pk[3]=(__bf16)v3;
        pk[4]=(__bf16)v4; pk[5]=(__bf16)v5; pk[6]=(__bf16)v6; pk[7]=(__bf16)v7;
        *(v8bf*)&xs[g * 1456 + q * 8] = pk;
    }

    v4f acc[4][4];
    #pragma unroll
    for (int a = 0; a < 4; ++a)
        #pragma unroll
        for (int b2 = 0; b2 < 4; ++b2) {
            v4f zz = {0.f, 0.f, 0.f, 0.f};
            acc[a][b2] = zz;
        }

    // per-lane A base: slab kg, rows wm*4.., col lr
    const u16* const a_base = &xs[kg * 1456 + (wm * 72 + lr) * 8];

    __syncthreads();   // the ONLY barrier: xs fully staged

    v8bf af[6];
    conv_step< 0>(b_base, a_base, af, bfP, acc);
    conv_step< 1>(b_base, a_base, af, bfP, acc);
    conv_step< 2>(b_base, a_base, af, bfP, acc);
    conv_step< 3>(b_base, a_base, af, bfP, acc);
    conv_step< 4>(b_base, a_base, af, bfP, acc);
    conv_step< 5>(b_base, a_base, af, bfP, acc);
    conv_step< 6>(b_base, a_base, af, bfP, acc);
    conv_step< 7>(b_base, a_base, af, bfP, acc);
    conv_step< 8>(b_base, a_base, af, bfP, acc);
    conv_step< 9>(b_base, a_base, af, bfP, acc);
    conv_step<10>(b_base, a_base, af, bfP, acc);
    conv_step<11>(b_base, a_base, af, bfP, acc);
    conv_step<12>(b_base, a_base, af, bfP, acc);
    conv_step<13>(b_base, a_base, af, bfP, acc);
    conv_step<14>(b_base, a_base, af, bfP, acc);
    conv_step<15>(b_base, a_base, af, bfP, acc);
    conv_step<16>(b_base, a_base, af, bfP, acc);
    conv_step<17>(b_base, a_base, af, bfP, acc);
    conv_step<18>(b_base, a_base, af, bfP, acc);
    conv_step<19>(b_base, a_base, af, bfP, acc);
    conv_step<20>(b_base, a_base, af, bfP, acc);
    conv_step<21>(b_base, a_base, af, bfP, acc);
    conv_step<22>(b_base, a_base, af, bfP, acc);
    conv_step<23>(b_base, a_base, af, bfP, acc);
    conv_step<24>(b_base, a_base, af, bfP, acc);
    conv_step<25>(b_base, a_base, af, bfP, acc);
    conv_step<26>(b_base, a_base, af, bfP, acc);
    conv_step<27>(b_base, a_base, af, bfP, acc);
    conv_step<28>(b_base, a_base, af, bfP, acc);
    conv_step<29>(b_base, a_base, af, bfP, acc);
    conv_step<30>(b_base, a_base, af, bfP, acc);
    conv_step<31>(b_base, a_base, af, bfP, acc);
    conv_step<32>(b_base, a_base, af, bfP, acc);
    conv_step<33>(b_base, a_base, af, bfP, acc);
    conv_step<34>(b_base, a_base, af, bfP, acc);
    conv_step<35>(b_base, a_base, af, bfP, acc);

    // ---- epilogue: + noise*strength + bias, lrelu * sqrt(2) ----
    const float ns = nstr[0];
    float cb4[4];
    #pragma unroll
    for (int ni = 0; ni < 4; ++ni)
        cb4[ni] = conv_b[wq * 64 + ni * 16 + lr];
    #pragma unroll
    for (int mi = 0; mi < 4; ++mi) {
        const int h = h0 + wm * 4 + mi;
        #pragma unroll
        for (int j = 0; j < 4; ++j) {
            const int w  = w0 + kg * 4 + j;
            const float nz = noise[((n << 8) + h) * 256 + w] * ns;
            float* orow = out + (size_t)((((n << 8) + h) << 8) + w) * 128;
            #pragma unroll
            for (int ni = 0; ni < 4; ++ni) {
                const int cout = wq * 64 + ni * 16 + lr;
                float v = acc[mi][ni][j] + nz + cb4[ni];
                v = (v < 0.f ? 0.2f * v : v) * LRELU_GAIN;
                orow[cout] = v;
            }
        }
    }
}

extern "C" void kernel_launch(void* const* d_in, const int* in_sizes, int n_in,
                              void* d_out, int out_size, void* d_ws, size_t ws_size,
                              hipStream_t stream) {
    const float* x     = (const float*)d_in[0];
    const float* dlat  = (const float*)d_in[1];
    const float* noise = (const float*)d_in[2];
    const float* aw    = (const float*)d_in[3];
    const float* ab    = (const float*)d_in[4];
    const float* cw    = (const float*)d_in[5];
    const float* cb    = (const float*)d_in[6];
    const float* nstr  = (const float*)d_in[7];
    const int*   lidx  = (const int*)d_in[8];
    float* out = (float*)d_out;

    float* s_buf = (float*)d_ws;                               // 4KB
    float* d_buf = (float*)((char*)d_ws + 4096);               // 4KB
    float* W2    = (float*)((char*)d_ws + 8192);
    u16*   wmod  = (u16*)((char*)d_ws + 8192);                 // 2.25MB (aliases W2, ordered)

    k_w2  <<<64,  256, 0, stream>>>(cw, W2);
    k_s   <<<8,   256, 0, stream>>>(dlat, aw, ab, lidx, s_buf);
    k_d   <<<8,   128, 0, stream>>>(W2, s_buf, d_buf);
    k_wmod<<<288, 256, 0, stream>>>(cw, s_buf, d_buf, wmod);
    k_conv<<<4096,256, 0, stream>>>(x, noise, cb, nstr, wmod, out);
}